// Round 9
// baseline (89.359 us; speedup 1.0000x reference)
//
#include <hip/hip_runtime.h>

// casConv2d: B=1, C=128, H=W=32, OC=128, K=3, pad=1, stride=1.
// L = 1024, CKK = 1152 = 36 exact 32-tap chunks (reference front-pad chunk == 0).
//
// Round-17. R8 post-mortem: 3 waves/SIMD regressed (71.1 vs 69.5) -> wave
// count isn't the limit. Correct issue model (m134: ds_read_b128 ~12cyc):
// R7's main loop reads 32 wave-uniform b128 x-broadcasts per chunk per
// thread -> per CU 8 waves x 9 chunks x 33 LDS ops x 12cyc = 28.5Kcyc =
// 11.9us ~= fused(14.5) - epilogue - prologue. LDS-ISSUE BOUND on x.
//
// R9: take x off the LDS pipe. Pre-build im2col xcol[b][j][tap][px] in ws
// (4.6MB, trivial kernel); fused reads chunk-x via readfirstlane-uniform
// pointer -> scalar s_load (SGPR feeds v_fma directly; worst case uniform
// L1-hit vector load, 4cyc vs 12). Main-loop LDS: 33 -> 1 op/chunk/thread.
// x-staging prologue + barrier deleted. W wt4 ping-pong, vbuf, and the
// verified epilogue untouched. xcol values are computed by the exact
// R5/R7 staging code (same gather, same predication) -> numerics
// bit-identical, absmax 0.03515625 expected.
#define L_    1024
#define CKK_  1152
#define QMAX_ 255.0f
#define NCH   36

// ---- W transpose: w[oc][1152] -> wt4[tq][oc] (tq = tap quad, 288x128 f4) ----
__global__ __launch_bounds__(256) void wtrans(
    const float* __restrict__ w, float* __restrict__ wt)
{
    const int e  = blockIdx.x * 256 + threadIdx.x;   // 36864 float4 slots
    const int oc = e / 288, tq = e - 288 * oc;
    const float4 v = ((const float4*)(w + oc * CKK_))[tq];   // coalesced read
    ((float4*)wt)[tq * 128 + oc] = v;                        // scattered write (L2)
}

// ---- im2col per fused-block: xcol[b][j][tap][px], 4608 floats/block ----
// Exact R5/R7 staging math (gather + zero-pad predication), global dest.
__global__ __launch_bounds__(256) void xcol_build(
    const float* __restrict__ x, float* __restrict__ xcol)
{
    const int b   = blockIdx.x;
    const int t   = threadIdx.x;
    const int oh  = b >> 3;
    const int ow0 = (b & 7) * 4;
    float* dst = xcol + b * 4608;
    for (int i = 0; i < 18; ++i) {
        const int e   = i * 256 + t;
        const int j   = e >> 7;            // chunk
        const int tap = (e >> 2) & 31;
        const int px  = e & 3;
        const int d   = j * 32 + tap;
        const int c   = d / 9, r = d - 9 * c;
        const int kh  = r / 3, kw = r - 3 * kh;
        const int iy  = oh + kh - 1, ix = ow0 + px + kw - 1;
        const bool ok = ((unsigned)iy < 32u) & ((unsigned)ix < 32u);
        const float vv = x[ok ? (c * 1024 + iy * 32 + ix) : 0];
        dst[e] = ok ? vv : 0.f;            // coalesced store
    }
}

template <bool FAST>
__global__ __launch_bounds__(512) void fused_cas(
    const float* __restrict__ x,      // [128][32][32]      (slow path staging)
    const float* __restrict__ w,      // [128][1152]        (slow path W)
    const float4* __restrict__ wt4,   // [288][128] float4  (FAST W)
    const float* __restrict__ xcol,   // [256][4608]        (FAST x, uniform)
    const float* __restrict__ bias,   // [128]
    float* __restrict__ out)          // [128][1024]
{
    __shared__ __align__(16) float4 vbuf[NCH][128];     // [j][oc] px0..3, 72 KB
    __shared__ __align__(16) float  xs[NCH * 32 * 4];   // slow path only, 18 KB
    __shared__ float red[8][4];                         // per-wave {mn0,mx0,mn1,mx1}
    __shared__ float spar[2][2][3];                     // [ppe][s]{sc,zp,iv}
    __shared__ float qb[4][128];                        // [px-local][oc]

    const int t   = threadIdx.x;                        // 0..511
    const int b   = blockIdx.x;
    const int oc  = t & 127;
    const int g   = t >> 7;            // chunk-ownership group (4 x 2 waves)
    const int ppe = g & 1;             // epilogue px-pair (threads 0..255)
    const int oh  = b >> 3;
    const int ow0 = (b & 7) * 4;
    const int l0  = b * 4;

    if constexpr (!FAST) {
        // slow-path prologue: stage ALL x to LDS (R7 code, 9/thread)
        for (int i = 0; i < 9; ++i) {
            const int e   = i * 512 + t;
            const int j   = e >> 7;
            const int tap = (e >> 2) & 31;
            const int px  = e & 3;
            const int d   = j * 32 + tap;
            const int c   = d / 9, r = d - 9 * c;
            const int kh  = r / 3, kw = r - 3 * kh;
            const int iy  = oh + kh - 1, ix = ow0 + px + kw - 1;
            const bool ok = ((unsigned)iy < 32u) & ((unsigned)ix < 32u);
            const float vv = x[ok ? (c * 1024 + iy * 32 + ix) : 0];
            xs[e] = ok ? vv : 0.f;
        }
        __syncthreads();
    }

    // uniform x base for this block (provably wave-uniform -> scalar loads)
    const float* xb = FAST
        ? (xcol + __builtin_amdgcn_readfirstlane(b * 4608)) : nullptr;

    // ---- main loop: group g owns chunks [9g, 9g+9) for ALL 4 px ----
    const float4* wrow = (const float4*)(w + oc * CKK_);

    auto load8 = [&](float4* dst, int j) {
#pragma unroll
        for (int k4 = 0; k4 < 8; ++k4)
            dst[k4] = FAST ? wt4[(j * 8 + k4) * 128 + oc] : wrow[j * 8 + k4];
    };

    auto chunk = [&](int j, const float4* wreg) {
        float a0 = 0.f, a1 = 0.f, a2 = 0.f, a3 = 0.f;
        const float* xj = FAST ? (xb + j * 128) : (xs + j * 128);
#pragma unroll
        for (int k4 = 0; k4 < 8; ++k4) {
            const float4 wv = wreg[k4];
            const float4 x0 = *(const float4*)(xj + (4 * k4 + 0) * 4);
            const float4 x1 = *(const float4*)(xj + (4 * k4 + 1) * 4);
            const float4 x2 = *(const float4*)(xj + (4 * k4 + 2) * 4);
            const float4 x3 = *(const float4*)(xj + (4 * k4 + 3) * 4);
            a0 = fmaf(wv.x, x0.x, a0); a1 = fmaf(wv.x, x0.y, a1);
            a2 = fmaf(wv.x, x0.z, a2); a3 = fmaf(wv.x, x0.w, a3);
            a0 = fmaf(wv.y, x1.x, a0); a1 = fmaf(wv.y, x1.y, a1);
            a2 = fmaf(wv.y, x1.z, a2); a3 = fmaf(wv.y, x1.w, a3);
            a0 = fmaf(wv.z, x2.x, a0); a1 = fmaf(wv.z, x2.y, a1);
            a2 = fmaf(wv.z, x2.z, a2); a3 = fmaf(wv.z, x2.w, a3);
            a0 = fmaf(wv.w, x3.x, a0); a1 = fmaf(wv.w, x3.y, a1);
            a2 = fmaf(wv.w, x3.z, a2); a3 = fmaf(wv.w, x3.w, a3);
        }
        vbuf[j][oc] = make_float4(a0, a1, a2, a3);   // group-private slot
    };

    {
        const int jb = g * 9;
        float4 wc[8], wn[8];
        load8(wc, jb);
#pragma unroll
        for (int jj = 0; jj < 8; jj += 2) {
            const int j0 = jb + jj;
            load8(wn, j0 + 1);              // prefetch while computing j0
            chunk(j0, wc);
            load8(wc, j0 + 2);              // jj<=6 -> jb+8 valid
            chunk(j0 + 1, wn);
        }
        chunk(jb + 8, wc);                  // tail (9th chunk)
    }
    __syncthreads();   // vbuf complete across groups

    // ---- totals: exact R5..R8 summation order (j ascending, then +bias).
    // Threads 256-511 compute benign duplicates.
    float s0 = 0.f, s1 = 0.f;
    for (int j = 0; j < NCH; ++j) {
        const float4 vv = vbuf[j][oc];
        s0 += (ppe == 0) ? vv.x : vv.z;
        s1 += (ppe == 0) ? vv.y : vv.w;
    }
    const float bval = bias[oc];
    const float t0 = s0 + bval, t1 = s1 + bval;

    // ---- minmax + scale/zp (verbatim R7, verified) ----
    float mn0 = t0, mx0 = t0, mn1 = t1, mx1 = t1;
#pragma unroll
    for (int off = 32; off > 0; off >>= 1) {
        mn0 = fminf(mn0, __shfl_xor(mn0, off));
        mx0 = fmaxf(mx0, __shfl_xor(mx0, off));
        mn1 = fminf(mn1, __shfl_xor(mn1, off));
        mx1 = fmaxf(mx1, __shfl_xor(mx1, off));
    }
    const int wv = t >> 6;                  // 0..7
    if ((t & 63) == 0) {
        red[wv][0] = mn0; red[wv][1] = mx0;
        red[wv][2] = mn1; red[wv][3] = mx1;
    }
    __syncthreads();
    if ((t & 63) == 0 && (wv & 1) == 0 && wv < 4) {  // waves 0,2 finalize ppe
        const int pw = wv ^ 1;
        const float amn0 = fminf(mn0, red[pw][0]);
        const float amx0 = fmaxf(mx0, red[pw][1]);
        const float amn1 = fminf(mn1, red[pw][2]);
        const float amx1 = fmaxf(mx1, red[pw][3]);
        {
            const float sv = (amx0 - amn0) / QMAX_;
            float z = -amn0 / sv;
            z = fmaxf(z, 0.f);      // fmaxf(NaN,0)=0 matches where(isnan,0)
            z = fminf(z, QMAX_);
            z = truncf(z);
            spar[ppe][0][0] = sv; spar[ppe][0][1] = z; spar[ppe][0][2] = 1.0f / sv;
        }
        {
            const float sv = (amx1 - amn1) / QMAX_;
            float z = -amn1 / sv;
            z = fmaxf(z, 0.f);
            z = fminf(z, QMAX_);
            z = truncf(z);
            spar[ppe][1][0] = sv; spar[ppe][1][1] = z; spar[ppe][1][2] = 1.0f / sv;
        }
    }
    __syncthreads();

    // ---- fake-quant accumulate (j ascending, same ops as R7) ----
    const float sc0 = spar[ppe][0][0], zp0 = spar[ppe][0][1], iv0 = spar[ppe][0][2];
    const float sc1 = spar[ppe][1][0], zp1 = spar[ppe][1][1], iv1 = spar[ppe][1][2];
    float q0 = 0.f, q1 = 0.f;
    for (int j = 0; j < NCH; ++j) {
        const float4 vv = vbuf[j][oc];
        const float v0 = (ppe == 0) ? vv.x : vv.z;
        const float v1 = (ppe == 0) ? vv.y : vv.w;
        float qn0 = rintf(v0 * iv0) + zp0;   // rintf == round-half-even
        qn0 = fminf(fmaxf(qn0, 0.f), QMAX_);
        q0 += (qn0 - zp0) * sc0;
        float qn1 = rintf(v1 * iv1) + zp1;
        qn1 = fminf(fmaxf(qn1, 0.f), QMAX_);
        q1 += (qn1 - zp1) * sc1;
    }
    if (t < 256) {
        qb[2 * ppe + 0][oc] = q0;
        qb[2 * ppe + 1][oc] = q1;
    }
    __syncthreads();

    if (t < 128)
        *(float4*)(out + (size_t)t * L_ + l0) =
            make_float4(qb[0][t], qb[1][t], qb[2][t], qb[3][t]);
}

extern "C" void kernel_launch(void* const* d_in, const int* in_sizes, int n_in,
                              void* d_out, int out_size, void* d_ws, size_t ws_size,
                              hipStream_t stream) {
    const float* x    = (const float*)d_in[0];  // 128*32*32
    const float* w    = (const float*)d_in[1];  // 128*1152
    const float* bias = (const float*)d_in[2];  // 128
    float* out = (float*)d_out;                 // 128*1024
    float* ws  = (float*)d_ws;

    const size_t wt_floats = (size_t)288 * 128 * 4;      // 147456 floats (576 KB)
    const size_t xc_floats = (size_t)256 * 4608;         // 1179648 floats (4.5 MB)
    const size_t need = (wt_floats + xc_floats) * 4;
    if (ws_size >= need) {
        float* wt = ws;
        float* xc = ws + wt_floats;
        wtrans<<<144, 256, 0, stream>>>(w, wt);
        xcol_build<<<256, 256, 0, stream>>>(x, xc);
        fused_cas<true><<<256, 512, 0, stream>>>(
            x, w, (const float4*)wt, xc, bias, out);
    } else {
        fused_cas<false><<<256, 512, 0, stream>>>(
            x, w, nullptr, nullptr, bias, out);
    }
}

// Round 10
// 71.218 us; speedup vs baseline: 1.2547x; 1.2547x over previous
//
#include <hip/hip_runtime.h>

// casConv2d: B=1, C=128, H=W=32, OC=128, K=3, pad=1, stride=1.
// L = 1024, CKK = 1152 = 36 exact 32-tap chunks (reference front-pad chunk == 0).
//
// Round-18. R9 post-mortem: scalar/uniform xcol reads REGRESSED (89.4 vs
// 69.5) -- 18KB/block thrashes the scalar K$ and s_loads return in-order
// with no overlap. Reverted. R9's DIAGNOSIS stands and matches R7 timing:
// fused is LDS-ISSUE bound (8 waves x 9 chunks x 33 ds_read_b128 x ~12cyc
// ~= 11.9us per CU). Fix must cut LDS instruction count on the LDS pipe.
//
// R10: halve broadcasts by doubling per-thread oc. Thread computes 2 oc x
// 4 px (oc pair 2*lane, 2*lane+1); groups = 1 wave (64 thr) covering all
// 128 oc; 8 groups own 4-5 chunks each (4x5+4x4=36, wave-uniform). Per
// chunk: x broadcasts stay 32 b128 but feed 8 outputs -> main-loop LDS/CU
// 2376 -> 1224 instrs (~6.1us). W doubles per thread (16 b128) but bytes/CU
// unchanged (576KB L2 stream, 4.3us floor, overlapped). wt4 reads stay
// coalesced (lanes read consecutive float4 pairs = 2KB/wave segment).
// Every (oc,px,chunk) partial keeps the exact ascending FMA chain; vbuf
// contents bit-identical; R7-verified epilogue verbatim -> absmax 0.03515625.
#define L_    1024
#define CKK_  1152
#define QMAX_ 255.0f
#define NCH   36

// ---- W transpose: w[oc][1152] -> wt4[tq][oc] (tq = tap quad, 288x128 f4) ----
__global__ __launch_bounds__(256) void wtrans(
    const float* __restrict__ w, float* __restrict__ wt)
{
    const int e  = blockIdx.x * 256 + threadIdx.x;   // 36864 float4 slots
    const int oc = e / 288, tq = e - 288 * oc;
    const float4 v = ((const float4*)(w + oc * CKK_))[tq];   // coalesced read
    ((float4*)wt)[tq * 128 + oc] = v;                        // scattered write (L2)
}

template <bool WT>
__global__ __launch_bounds__(512) void fused_cas(
    const float* __restrict__ x,      // [128][32][32]
    const float* __restrict__ w,      // [128][1152]        (WT=false path)
    const float4* __restrict__ wt4,   // [288][128] float4  (WT=true path)
    const float* __restrict__ bias,   // [128]
    float* __restrict__ out)          // [128][1024]
{
    __shared__ __align__(16) float  xs[NCH * 32 * 4];   // [j][tap][px], 18 KB
    __shared__ __align__(16) float4 vbuf[NCH][128];     // [j][oc] px0..3, 72 KB
    __shared__ float red[8][4];                         // per-wave {mn0,mx0,mn1,mx1}
    __shared__ float spar[2][2][3];                     // [ppe][s]{sc,zp,iv}
    __shared__ float qb[4][128];                        // [px-local][oc]

    const int t    = threadIdx.x;                       // 0..511
    const int b    = blockIdx.x;
    const int lane = t & 63;
    const int g    = t >> 6;           // wave-group 0..7 (chunk ownership)
    const int oc0  = 2 * lane;         // oc pair {oc0, oc0+1}
    const int oc   = t & 127;          // epilogue oc
    const int ppe  = (t >> 7) & 1;     // epilogue px-pair (threads 0..255)
    const int oh   = b >> 3;           // all 4 px share one output row
    const int ow0  = (b & 7) * 4;
    const int l0   = b * 4;

    // ---- prologue: stage ALL x for this block (4608 elems = 9/thread) ----
    for (int i = 0; i < 9; ++i) {
        const int e   = i * 512 + t;
        const int j   = e >> 7;            // chunk
        const int tap = (e >> 2) & 31;
        const int px  = e & 3;
        const int d   = j * 32 + tap;
        const int c   = d / 9, r = d - 9 * c;
        const int kh  = r / 3, kw = r - 3 * kh;
        const int iy  = oh + kh - 1, ix = ow0 + px + kw - 1;
        const bool ok = ((unsigned)iy < 32u) & ((unsigned)ix < 32u);
        const float vv = x[ok ? (c * 1024 + iy * 32 + ix) : 0];
        xs[e] = ok ? vv : 0.f;
    }
    __syncthreads();

    // ---- main loop: wave g owns chunks [jb, jb+n), n=5 for g<4 else 4 ----
    const bool five = (g < 4);
    const int  jb   = five ? (5 * g) : (4 * g + 4);

    const float4* wrow0 = (const float4*)(w + (oc0 + 0) * CKK_);
    const float4* wrow1 = (const float4*)(w + (oc0 + 1) * CKK_);

    auto load16 = [&](float4* dst, int j) {
#pragma unroll
        for (int k4 = 0; k4 < 8; ++k4) {
            dst[2 * k4 + 0] = WT ? wt4[(j * 8 + k4) * 128 + oc0]     : wrow0[j * 8 + k4];
            dst[2 * k4 + 1] = WT ? wt4[(j * 8 + k4) * 128 + oc0 + 1] : wrow1[j * 8 + k4];
        }
    };

    auto chunk2 = [&](int j, const float4* wreg) {
        float a0 = 0.f, a1 = 0.f, a2 = 0.f, a3 = 0.f;   // oc0,   px0..3
        float a4 = 0.f, a5 = 0.f, a6 = 0.f, a7 = 0.f;   // oc0+1, px0..3
        const float4* xj = (const float4*)(xs + j * 128);  // [tap] -> 4 px
#pragma unroll
        for (int k4 = 0; k4 < 8; ++k4) {
            const float4 w0 = wreg[2 * k4 + 0];
            const float4 w1 = wreg[2 * k4 + 1];
            const float4 x0 = xj[4 * k4 + 0];
            const float4 x1 = xj[4 * k4 + 1];
            const float4 x2 = xj[4 * k4 + 2];
            const float4 x3 = xj[4 * k4 + 3];
            // oc0 chain: identical order to R7 (k4 asc; taps .x,.y,.z,.w)
            a0 = fmaf(w0.x, x0.x, a0); a1 = fmaf(w0.x, x0.y, a1);
            a2 = fmaf(w0.x, x0.z, a2); a3 = fmaf(w0.x, x0.w, a3);
            a0 = fmaf(w0.y, x1.x, a0); a1 = fmaf(w0.y, x1.y, a1);
            a2 = fmaf(w0.y, x1.z, a2); a3 = fmaf(w0.y, x1.w, a3);
            a0 = fmaf(w0.z, x2.x, a0); a1 = fmaf(w0.z, x2.y, a1);
            a2 = fmaf(w0.z, x2.z, a2); a3 = fmaf(w0.z, x2.w, a3);
            a0 = fmaf(w0.w, x3.x, a0); a1 = fmaf(w0.w, x3.y, a1);
            a2 = fmaf(w0.w, x3.z, a2); a3 = fmaf(w0.w, x3.w, a3);
            // oc0+1 chain: same order
            a4 = fmaf(w1.x, x0.x, a4); a5 = fmaf(w1.x, x0.y, a5);
            a6 = fmaf(w1.x, x0.z, a6); a7 = fmaf(w1.x, x0.w, a7);
            a4 = fmaf(w1.y, x1.x, a4); a5 = fmaf(w1.y, x1.y, a5);
            a6 = fmaf(w1.y, x1.z, a6); a7 = fmaf(w1.y, x1.w, a7);
            a4 = fmaf(w1.z, x2.x, a4); a5 = fmaf(w1.z, x2.y, a5);
            a6 = fmaf(w1.z, x2.z, a6); a7 = fmaf(w1.z, x2.w, a7);
            a4 = fmaf(w1.w, x3.x, a4); a5 = fmaf(w1.w, x3.y, a5);
            a6 = fmaf(w1.w, x3.z, a6); a7 = fmaf(w1.w, x3.w, a7);
        }
        vbuf[j][oc0 + 0] = make_float4(a0, a1, a2, a3);   // group-private slots
        vbuf[j][oc0 + 1] = make_float4(a4, a5, a6, a7);
    };

    {
        float4 wc[16], wn[16];
        load16(wc, jb + 0);
        load16(wn, jb + 1);
        chunk2(jb + 0, wc); load16(wc, jb + 2);
        chunk2(jb + 1, wn); load16(wn, jb + 3);
        chunk2(jb + 2, wc); if (five) load16(wc, jb + 4);
        chunk2(jb + 3, wn);
        if (five) chunk2(jb + 4, wc);   // uniform per wave (g<4), no divergence
    }
    __syncthreads();   // vbuf complete across waves

    // ---- totals: exact R5..R9 summation order (j ascending, then +bias).
    // Threads 256-511 compute benign duplicates.
    float s0 = 0.f, s1 = 0.f;
    for (int j = 0; j < NCH; ++j) {
        const float4 vv = vbuf[j][oc];
        s0 += (ppe == 0) ? vv.x : vv.z;
        s1 += (ppe == 0) ? vv.y : vv.w;
    }
    const float bval = bias[oc];
    const float t0 = s0 + bval, t1 = s1 + bval;

    // ---- minmax + scale/zp (verbatim R7, verified) ----
    float mn0 = t0, mx0 = t0, mn1 = t1, mx1 = t1;
#pragma unroll
    for (int off = 32; off > 0; off >>= 1) {
        mn0 = fminf(mn0, __shfl_xor(mn0, off));
        mx0 = fmaxf(mx0, __shfl_xor(mx0, off));
        mn1 = fminf(mn1, __shfl_xor(mn1, off));
        mx1 = fmaxf(mx1, __shfl_xor(mx1, off));
    }
    const int wv = t >> 6;                  // 0..7
    if ((t & 63) == 0) {
        red[wv][0] = mn0; red[wv][1] = mx0;
        red[wv][2] = mn1; red[wv][3] = mx1;
    }
    __syncthreads();
    if ((t & 63) == 0 && (wv & 1) == 0 && wv < 4) {  // waves 0,2 finalize ppe
        const int pw = wv ^ 1;
        const float amn0 = fminf(mn0, red[pw][0]);
        const float amx0 = fmaxf(mx0, red[pw][1]);
        const float amn1 = fminf(mn1, red[pw][2]);
        const float amx1 = fmaxf(mx1, red[pw][3]);
        {
            const float sv = (amx0 - amn0) / QMAX_;
            float z = -amn0 / sv;
            z = fmaxf(z, 0.f);      // fmaxf(NaN,0)=0 matches where(isnan,0)
            z = fminf(z, QMAX_);
            z = truncf(z);
            spar[ppe][0][0] = sv; spar[ppe][0][1] = z; spar[ppe][0][2] = 1.0f / sv;
        }
        {
            const float sv = (amx1 - amn1) / QMAX_;
            float z = -amn1 / sv;
            z = fmaxf(z, 0.f);
            z = fminf(z, QMAX_);
            z = truncf(z);
            spar[ppe][1][0] = sv; spar[ppe][1][1] = z; spar[ppe][1][2] = 1.0f / sv;
        }
    }
    __syncthreads();

    // ---- fake-quant accumulate (j ascending, same ops as R7) ----
    const float sc0 = spar[ppe][0][0], zp0 = spar[ppe][0][1], iv0 = spar[ppe][0][2];
    const float sc1 = spar[ppe][1][0], zp1 = spar[ppe][1][1], iv1 = spar[ppe][1][2];
    float q0 = 0.f, q1 = 0.f;
    for (int j = 0; j < NCH; ++j) {
        const float4 vv = vbuf[j][oc];
        const float v0 = (ppe == 0) ? vv.x : vv.z;
        const float v1 = (ppe == 0) ? vv.y : vv.w;
        float qn0 = rintf(v0 * iv0) + zp0;   // rintf == round-half-even
        qn0 = fminf(fmaxf(qn0, 0.f), QMAX_);
        q0 += (qn0 - zp0) * sc0;
        float qn1 = rintf(v1 * iv1) + zp1;
        qn1 = fminf(fmaxf(qn1, 0.f), QMAX_);
        q1 += (qn1 - zp1) * sc1;
    }
    if (t < 256) {
        qb[2 * ppe + 0][oc] = q0;
        qb[2 * ppe + 1][oc] = q1;
    }
    __syncthreads();

    if (t < 128)
        *(float4*)(out + (size_t)t * L_ + l0) =
            make_float4(qb[0][t], qb[1][t], qb[2][t], qb[3][t]);
}

extern "C" void kernel_launch(void* const* d_in, const int* in_sizes, int n_in,
                              void* d_out, int out_size, void* d_ws, size_t ws_size,
                              hipStream_t stream) {
    const float* x    = (const float*)d_in[0];  // 128*32*32
    const float* w    = (const float*)d_in[1];  // 128*1152
    const float* bias = (const float*)d_in[2];  // 128
    float* out = (float*)d_out;                 // 128*1024
    float* ws  = (float*)d_ws;

    const size_t wt_need = (size_t)288 * 128 * 16;   // 576 KB
    if (ws_size >= wt_need) {
        wtrans<<<144, 256, 0, stream>>>(w, ws);
        fused_cas<true><<<256, 512, 0, stream>>>(
            x, w, (const float4*)ws, bias, out);
    } else {
        fused_cas<false><<<256, 512, 0, stream>>>(
            x, w, nullptr, bias, out);
    }
}

// Round 11
// 70.320 us; speedup vs baseline: 1.2707x; 1.0128x over previous
//
#include <hip/hip_runtime.h>

// casConv2d: B=1, C=128, H=W=32, OC=128, K=3, pad=1, stride=1.
// L = 1024, CKK = 1152 = 36 exact 32-tap chunks (reference front-pad chunk == 0).
//
// Round-19. R10 post-mortem: halving LDS broadcasts gave NOTHING (71.2 vs
// 69.5) and 3 waves/SIMD gave nothing (R8) -> main loop is NOT LDS-issue
// bound (x reads are same-address broadcasts, cheap). Calibrated budget:
// fill 40.3 + fixed overhead 11.4 (R5-direct) + wtrans ~2.5 + fused ~15.3.
// fused = FMA 1.9 (VALUBusy 12% check) + W L2 stream 4.4us floor + serial/
// duplicated overhead: x-prologue before any W issue, epilogue LDS loops
// run by 8 waves though 4 suffice, W prefetch only 1-deep.
//
// R11 = R7 (the 69.5 winner, 1 oc x 4 px, 4 groups x 9 chunks) + 3 trims:
//  (1) hoist chunk-0/1 W prefetch above the x prologue (L2 latency hides
//      under staging);
//  (2) gate epilogue totals/quant loops to t<256 (barriers unconditional)
//      -> halves epilogue LDS-pipe traffic;
//  (3) 2-deep rotating W prefetch (3 named buffers, fully unrolled, static
//      indexing -> no spill; ~170 VGPR < 256 cap at 2 waves/SIMD).
// FMA chains, vbuf contents, totals order, quant ops verbatim R7 ->
// bit-identical, absmax 0.03515625 expected.
#define L_    1024
#define CKK_  1152
#define QMAX_ 255.0f
#define NCH   36

// ---- W transpose: w[oc][1152] -> wt4[tq][oc] (tq = tap quad, 288x128 f4) ----
__global__ __launch_bounds__(256) void wtrans(
    const float* __restrict__ w, float* __restrict__ wt)
{
    const int e  = blockIdx.x * 256 + threadIdx.x;   // 36864 float4 slots
    const int oc = e / 288, tq = e - 288 * oc;
    const float4 v = ((const float4*)(w + oc * CKK_))[tq];   // coalesced read
    ((float4*)wt)[tq * 128 + oc] = v;                        // scattered write (L2)
}

template <bool WT>
__global__ __launch_bounds__(512) void fused_cas(
    const float* __restrict__ x,      // [128][32][32]
    const float* __restrict__ w,      // [128][1152]        (WT=false path)
    const float4* __restrict__ wt4,   // [288][128] float4  (WT=true path)
    const float* __restrict__ bias,   // [128]
    float* __restrict__ out)          // [128][1024]
{
    __shared__ __align__(16) float  xs[NCH * 32 * 4];   // [j][tap][px], 18 KB
    __shared__ __align__(16) float4 vbuf[NCH][128];     // [j][oc] px0..3, 72 KB
    __shared__ float red[8][4];                         // per-wave {mn0,mx0,mn1,mx1}
    __shared__ float spar[2][2][3];                     // [ppe][s]{sc,zp,iv}
    __shared__ float qb[4][128];                        // [px-local][oc]

    const int t   = threadIdx.x;                        // 0..511
    const int b   = blockIdx.x;
    const int oc  = t & 127;
    const int g   = t >> 7;            // chunk-ownership group (4 x 2 waves)
    const int ppe = g & 1;             // epilogue px-pair (threads 0..255)
    const int oh  = b >> 3;            // all 4 px share one output row
    const int ow0 = (b & 7) * 4;
    const int l0  = b * 4;
    const int jb  = g * 9;

    const float4* wrow = (const float4*)(w + oc * CKK_);

    auto load8 = [&](float4* dst, int j) {
#pragma unroll
        for (int k4 = 0; k4 < 8; ++k4)
            dst[k4] = WT ? wt4[(j * 8 + k4) * 128 + oc] : wrow[j * 8 + k4];
    };

    // (1) issue chunk jb, jb+1 W loads FIRST: L2 latency hides under staging
    float4 wA[8], wB[8], wC[8];
    load8(wA, jb + 0);
    load8(wB, jb + 1);

    // ---- prologue: stage ALL x for this block (4608 elems = 9/thread) ----
    for (int i = 0; i < 9; ++i) {
        const int e   = i * 512 + t;
        const int j   = e >> 7;            // chunk
        const int tap = (e >> 2) & 31;
        const int px  = e & 3;
        const int d   = j * 32 + tap;
        const int c   = d / 9, r = d - 9 * c;
        const int kh  = r / 3, kw = r - 3 * kh;
        const int iy  = oh + kh - 1, ix = ow0 + px + kw - 1;
        const bool ok = ((unsigned)iy < 32u) & ((unsigned)ix < 32u);
        const float vv = x[ok ? (c * 1024 + iy * 32 + ix) : 0];
        xs[e] = ok ? vv : 0.f;
    }
    __syncthreads();

    // ---- main loop: group g owns chunks [jb, jb+9) for ALL 4 px ----
    auto chunk = [&](int j, const float4* wreg) {
        float a0 = 0.f, a1 = 0.f, a2 = 0.f, a3 = 0.f;
        const float4* xj = (const float4*)(xs + j * 128);  // [tap] -> 4 px
#pragma unroll
        for (int k4 = 0; k4 < 8; ++k4) {
            const float4 wv = wreg[k4];
            const float4 x0 = xj[4 * k4 + 0];
            const float4 x1 = xj[4 * k4 + 1];
            const float4 x2 = xj[4 * k4 + 2];
            const float4 x3 = xj[4 * k4 + 3];
            a0 = fmaf(wv.x, x0.x, a0); a1 = fmaf(wv.x, x0.y, a1);
            a2 = fmaf(wv.x, x0.z, a2); a3 = fmaf(wv.x, x0.w, a3);
            a0 = fmaf(wv.y, x1.x, a0); a1 = fmaf(wv.y, x1.y, a1);
            a2 = fmaf(wv.y, x1.z, a2); a3 = fmaf(wv.y, x1.w, a3);
            a0 = fmaf(wv.z, x2.x, a0); a1 = fmaf(wv.z, x2.y, a1);
            a2 = fmaf(wv.z, x2.z, a2); a3 = fmaf(wv.z, x2.w, a3);
            a0 = fmaf(wv.w, x3.x, a0); a1 = fmaf(wv.w, x3.y, a1);
            a2 = fmaf(wv.w, x3.z, a2); a3 = fmaf(wv.w, x3.w, a3);
        }
        vbuf[j][oc] = make_float4(a0, a1, a2, a3);   // group-private slot
    };

    // (3) 2-deep rotating prefetch, fully unrolled (static buffer names)
    load8(wC, jb + 2); chunk(jb + 0, wA);
    load8(wA, jb + 3); chunk(jb + 1, wB);
    load8(wB, jb + 4); chunk(jb + 2, wC);
    load8(wC, jb + 5); chunk(jb + 3, wA);
    load8(wA, jb + 6); chunk(jb + 4, wB);
    load8(wB, jb + 7); chunk(jb + 5, wC);
    load8(wC, jb + 8); chunk(jb + 6, wA);
    chunk(jb + 7, wB);
    chunk(jb + 8, wC);
    __syncthreads();   // vbuf complete across groups

    // ---- epilogue, gated to threads 0..255 (2) ----
    // Totals: exact R5..R10 summation order (j ascending, then +bias).
    float t0 = 0.f, t1 = 0.f;
    float mn0 = 0.f, mx0 = 0.f, mn1 = 0.f, mx1 = 0.f;
    const int wv = t >> 6;                  // 0..7
    if (t < 256) {                          // wave-uniform branch (waves 0-3)
        float s0 = 0.f, s1 = 0.f;
        for (int j = 0; j < NCH; ++j) {
            const float4 vv = vbuf[j][oc];
            s0 += (ppe == 0) ? vv.x : vv.z;
            s1 += (ppe == 0) ? vv.y : vv.w;
        }
        const float bval = bias[oc];
        t0 = s0 + bval; t1 = s1 + bval;

        mn0 = t0; mx0 = t0; mn1 = t1; mx1 = t1;
#pragma unroll
        for (int off = 32; off > 0; off >>= 1) {
            mn0 = fminf(mn0, __shfl_xor(mn0, off));
            mx0 = fmaxf(mx0, __shfl_xor(mx0, off));
            mn1 = fminf(mn1, __shfl_xor(mn1, off));
            mx1 = fmaxf(mx1, __shfl_xor(mx1, off));
        }
        if ((t & 63) == 0) {
            red[wv][0] = mn0; red[wv][1] = mx0;
            red[wv][2] = mn1; red[wv][3] = mx1;
        }
    }
    __syncthreads();
    if ((t & 63) == 0 && (wv & 1) == 0 && wv < 4) {  // waves 0,2 finalize ppe
        const int pw = wv ^ 1;
        const float amn0 = fminf(mn0, red[pw][0]);
        const float amx0 = fmaxf(mx0, red[pw][1]);
        const float amn1 = fminf(mn1, red[pw][2]);
        const float amx1 = fmaxf(mx1, red[pw][3]);
        {
            const float sv = (amx0 - amn0) / QMAX_;
            float z = -amn0 / sv;
            z = fmaxf(z, 0.f);      // fmaxf(NaN,0)=0 matches where(isnan,0)
            z = fminf(z, QMAX_);
            z = truncf(z);
            spar[ppe][0][0] = sv; spar[ppe][0][1] = z; spar[ppe][0][2] = 1.0f / sv;
        }
        {
            const float sv = (amx1 - amn1) / QMAX_;
            float z = -amn1 / sv;
            z = fmaxf(z, 0.f);
            z = fminf(z, QMAX_);
            z = truncf(z);
            spar[ppe][1][0] = sv; spar[ppe][1][1] = z; spar[ppe][1][2] = 1.0f / sv;
        }
    }
    __syncthreads();

    if (t < 256) {                          // fake-quant accumulate (j asc)
        const float sc0 = spar[ppe][0][0], zp0 = spar[ppe][0][1], iv0 = spar[ppe][0][2];
        const float sc1 = spar[ppe][1][0], zp1 = spar[ppe][1][1], iv1 = spar[ppe][1][2];
        float q0 = 0.f, q1 = 0.f;
        for (int j = 0; j < NCH; ++j) {
            const float4 vv = vbuf[j][oc];
            const float v0 = (ppe == 0) ? vv.x : vv.z;
            const float v1 = (ppe == 0) ? vv.y : vv.w;
            float qn0 = rintf(v0 * iv0) + zp0;   // rintf == round-half-even
            qn0 = fminf(fmaxf(qn0, 0.f), QMAX_);
            q0 += (qn0 - zp0) * sc0;
            float qn1 = rintf(v1 * iv1) + zp1;
            qn1 = fminf(fmaxf(qn1, 0.f), QMAX_);
            q1 += (qn1 - zp1) * sc1;
        }
        qb[2 * ppe + 0][oc] = q0;
        qb[2 * ppe + 1][oc] = q1;
    }
    __syncthreads();

    if (t < 128)
        *(float4*)(out + (size_t)t * L_ + l0) =
            make_float4(qb[0][t], qb[1][t], qb[2][t], qb[3][t]);
}

extern "C" void kernel_launch(void* const* d_in, const int* in_sizes, int n_in,
                              void* d_out, int out_size, void* d_ws, size_t ws_size,
                              hipStream_t stream) {
    const float* x    = (const float*)d_in[0];  // 128*32*32
    const float* w    = (const float*)d_in[1];  // 128*1152
    const float* bias = (const float*)d_in[2];  // 128
    float* out = (float*)d_out;                 // 128*1024
    float* ws  = (float*)d_ws;

    const size_t wt_need = (size_t)288 * 128 * 16;   // 576 KB
    if (ws_size >= wt_need) {
        wtrans<<<144, 256, 0, stream>>>(w, ws);
        fused_cas<true><<<256, 512, 0, stream>>>(
            x, w, (const float4*)ws, bias, out);
    } else {
        fused_cas<false><<<256, 512, 0, stream>>>(
            x, w, nullptr, bias, out);
    }
}

// Round 12
// 67.738 us; speedup vs baseline: 1.3192x; 1.0381x over previous
//
#include <hip/hip_runtime.h>

// casConv2d: B=1, C=128, H=W=32, OC=128, K=3, pad=1, stride=1.
// L = 1024, CKK = 1152 = 36 exact 32-tap chunks (reference front-pad chunk == 0).
//
// Round-20. R8/R10/R11 all nulled (69.5-71.2): wave count, LDS-broadcast
// count, prefetch depth, epilogue gating don't move fused off ~15-16us.
// VALUBusy 12% x 15us = 1.8us FMA -> waves ~90% stalled on the one structure
// never touched: the vbuf round-trip (36 f4 LDS writes + two 36-iter
// dependent LDS-accumulate loops per thread; 93KB LDS).
//
// R12: eliminate vbuf. Group g holds its 9 chunk-partials in 9 NAMED float4
// registers (36 VGPR, static -> no R2-style spill). Reductions: in-register
// group sum (j-ascending) -> 8KB LDS exchange -> totals g0+g1+g2+g3 ->
// verbatim minmax/scale -> each thread quantizes its 9 register partials
// (j-ascending in group) -> 8KB exchange -> g-ascending final sum -> f4 store.
// LDS 93KB -> ~27KB; epilogue LDS ops ~10x down.
// NUMERICS: totals/quant sums reassociate at group boundaries ONLY
// ((Sg0)+(Sg1)+(Sg2)+(Sg3) vs flat j-ascending); within-group order and all
// quant ops verbatim. absmax may shift slightly from 0.03515625 (same
// one-quant-step error class).
#define L_    1024
#define CKK_  1152
#define QMAX_ 255.0f
#define NCH   36

static __device__ __forceinline__ float4 f4add(float4 a, float4 b) {
    return make_float4(a.x + b.x, a.y + b.y, a.z + b.z, a.w + b.w);
}

// ---- W transpose: w[oc][1152] -> wt4[tq][oc] (tq = tap quad, 288x128 f4) ----
__global__ __launch_bounds__(256) void wtrans(
    const float* __restrict__ w, float* __restrict__ wt)
{
    const int e  = blockIdx.x * 256 + threadIdx.x;   // 36864 float4 slots
    const int oc = e / 288, tq = e - 288 * oc;
    const float4 v = ((const float4*)(w + oc * CKK_))[tq];   // coalesced read
    ((float4*)wt)[tq * 128 + oc] = v;                        // scattered write (L2)
}

template <bool WT>
__global__ __launch_bounds__(512) void fused_cas(
    const float* __restrict__ x,      // [128][32][32]
    const float* __restrict__ w,      // [128][1152]        (WT=false path)
    const float4* __restrict__ wt4,   // [288][128] float4  (WT=true path)
    const float* __restrict__ bias,   // [128]
    float* __restrict__ out)          // [128][1024]
{
    __shared__ __align__(16) float  xs[NCH * 32 * 4];   // [j][tap][px], 18 KB
    __shared__ __align__(16) float4 gx[4][128];         // group exchange, 8 KB
    __shared__ float red[8][4];                         // per-wave {mn0,mx0,mn1,mx1}
    __shared__ float spar4[4][3];                       // [px]{sc,zp,iv}

    const int t   = threadIdx.x;                        // 0..511
    const int b   = blockIdx.x;
    const int oc  = t & 127;
    const int g   = t >> 7;            // chunk-ownership group (4 x 2 waves)
    const int ppe = g & 1;             // epilogue px-pair (threads 0..255)
    const int oh  = b >> 3;            // all 4 px share one output row
    const int ow0 = (b & 7) * 4;
    const int l0  = b * 4;
    const int jb  = g * 9;

    const float4* wrow = (const float4*)(w + oc * CKK_);

    auto load8 = [&](float4* dst, int j) {
#pragma unroll
        for (int k4 = 0; k4 < 8; ++k4)
            dst[k4] = WT ? wt4[(j * 8 + k4) * 128 + oc] : wrow[j * 8 + k4];
    };

    // issue chunk jb, jb+1 W loads first: L2 latency hides under x staging
    float4 wA[8], wB[8];
    load8(wA, jb + 0);
    load8(wB, jb + 1);

    // ---- prologue: stage ALL x for this block (4608 elems = 9/thread) ----
    for (int i = 0; i < 9; ++i) {
        const int e   = i * 512 + t;
        const int j   = e >> 7;            // chunk
        const int tap = (e >> 2) & 31;
        const int px  = e & 3;
        const int d   = j * 32 + tap;
        const int c   = d / 9, r = d - 9 * c;
        const int kh  = r / 3, kw = r - 3 * kh;
        const int iy  = oh + kh - 1, ix = ow0 + px + kw - 1;
        const bool ok = ((unsigned)iy < 32u) & ((unsigned)ix < 32u);
        const float vv = x[ok ? (c * 1024 + iy * 32 + ix) : 0];
        xs[e] = ok ? vv : 0.f;
    }
    __syncthreads();

    // ---- main loop: group g owns chunks [jb, jb+9); partials in registers ----
    auto chunk = [&](int j, const float4* wreg) -> float4 {
        float a0 = 0.f, a1 = 0.f, a2 = 0.f, a3 = 0.f;
        const float4* xj = (const float4*)(xs + j * 128);  // [tap] -> 4 px
#pragma unroll
        for (int k4 = 0; k4 < 8; ++k4) {
            const float4 wv = wreg[k4];
            const float4 x0 = xj[4 * k4 + 0];
            const float4 x1 = xj[4 * k4 + 1];
            const float4 x2 = xj[4 * k4 + 2];
            const float4 x3 = xj[4 * k4 + 3];
            a0 = fmaf(wv.x, x0.x, a0); a1 = fmaf(wv.x, x0.y, a1);
            a2 = fmaf(wv.x, x0.z, a2); a3 = fmaf(wv.x, x0.w, a3);
            a0 = fmaf(wv.y, x1.x, a0); a1 = fmaf(wv.y, x1.y, a1);
            a2 = fmaf(wv.y, x1.z, a2); a3 = fmaf(wv.y, x1.w, a3);
            a0 = fmaf(wv.z, x2.x, a0); a1 = fmaf(wv.z, x2.y, a1);
            a2 = fmaf(wv.z, x2.z, a2); a3 = fmaf(wv.z, x2.w, a3);
            a0 = fmaf(wv.w, x3.x, a0); a1 = fmaf(wv.w, x3.y, a1);
            a2 = fmaf(wv.w, x3.z, a2); a3 = fmaf(wv.w, x3.w, a3);
        }
        return make_float4(a0, a1, a2, a3);
    };

    float4 p0, p1, p2, p3, p4, p5, p6, p7, p8;   // named -> static, no scratch
    p0 = chunk(jb + 0, wA); load8(wA, jb + 2);
    p1 = chunk(jb + 1, wB); load8(wB, jb + 3);
    p2 = chunk(jb + 2, wA); load8(wA, jb + 4);
    p3 = chunk(jb + 3, wB); load8(wB, jb + 5);
    p4 = chunk(jb + 4, wA); load8(wA, jb + 6);
    p5 = chunk(jb + 5, wB); load8(wB, jb + 7);
    p6 = chunk(jb + 6, wA); load8(wA, jb + 8);
    p7 = chunk(jb + 7, wB);
    p8 = chunk(jb + 8, wA);

    // group sum, j ascending within group
    float4 gs = p0;
    gs = f4add(gs, p1); gs = f4add(gs, p2); gs = f4add(gs, p3);
    gs = f4add(gs, p4); gs = f4add(gs, p5); gs = f4add(gs, p6);
    gs = f4add(gs, p7); gs = f4add(gs, p8);
    gx[g][oc] = gs;
    __syncthreads();

    // ---- totals + minmax (threads 0..255; g-ascending cross-group sum) ----
    float t0 = 0.f, t1 = 0.f;
    float mn0 = 0.f, mx0 = 0.f, mn1 = 0.f, mx1 = 0.f;
    const int wv = t >> 6;                  // 0..7
    if (t < 256) {
        float4 s = gx[0][oc];
        s = f4add(s, gx[1][oc]);
        s = f4add(s, gx[2][oc]);
        s = f4add(s, gx[3][oc]);
        const float bval = bias[oc];
        t0 = ((ppe == 0) ? s.x : s.z) + bval;
        t1 = ((ppe == 0) ? s.y : s.w) + bval;

        mn0 = t0; mx0 = t0; mn1 = t1; mx1 = t1;
#pragma unroll
        for (int off = 32; off > 0; off >>= 1) {
            mn0 = fminf(mn0, __shfl_xor(mn0, off));
            mx0 = fmaxf(mx0, __shfl_xor(mx0, off));
            mn1 = fminf(mn1, __shfl_xor(mn1, off));
            mx1 = fmaxf(mx1, __shfl_xor(mx1, off));
        }
        if ((t & 63) == 0) {
            red[wv][0] = mn0; red[wv][1] = mx0;
            red[wv][2] = mn1; red[wv][3] = mx1;
        }
    }
    __syncthreads();
    if ((t & 63) == 0 && (wv & 1) == 0 && wv < 4) {  // waves 0,2 finalize ppe
        const int pw = wv ^ 1;
        const float amn0 = fminf(mn0, red[pw][0]);
        const float amx0 = fmaxf(mx0, red[pw][1]);
        const float amn1 = fminf(mn1, red[pw][2]);
        const float amx1 = fmaxf(mx1, red[pw][3]);
        {
            const float sv = (amx0 - amn0) / QMAX_;
            float z = -amn0 / sv;
            z = fmaxf(z, 0.f);      // fmaxf(NaN,0)=0 matches where(isnan,0)
            z = fminf(z, QMAX_);
            z = truncf(z);
            spar4[2 * ppe + 0][0] = sv; spar4[2 * ppe + 0][1] = z;
            spar4[2 * ppe + 0][2] = 1.0f / sv;
        }
        {
            const float sv = (amx1 - amn1) / QMAX_;
            float z = -amn1 / sv;
            z = fmaxf(z, 0.f);
            z = fminf(z, QMAX_);
            z = truncf(z);
            spar4[2 * ppe + 1][0] = sv; spar4[2 * ppe + 1][1] = z;
            spar4[2 * ppe + 1][2] = 1.0f / sv;
        }
    }
    __syncthreads();

    // ---- fake-quant of register-held partials (all threads, j asc in group) ----
    {
        const float scx = spar4[0][0], zpx = spar4[0][1], ivx = spar4[0][2];
        const float scy = spar4[1][0], zpy = spar4[1][1], ivy = spar4[1][2];
        const float scz = spar4[2][0], zpz = spar4[2][1], ivz = spar4[2][2];
        const float scw = spar4[3][0], zpw = spar4[3][1], ivw = spar4[3][2];

        float qx = 0.f, qy = 0.f, qz = 0.f, qw = 0.f;
        auto qstep = [&](const float4 p) {
            float n;
            n = rintf(p.x * ivx) + zpx; n = fminf(fmaxf(n, 0.f), QMAX_); qx += (n - zpx) * scx;
            n = rintf(p.y * ivy) + zpy; n = fminf(fmaxf(n, 0.f), QMAX_); qy += (n - zpy) * scy;
            n = rintf(p.z * ivz) + zpz; n = fminf(fmaxf(n, 0.f), QMAX_); qz += (n - zpz) * scz;
            n = rintf(p.w * ivw) + zpw; n = fminf(fmaxf(n, 0.f), QMAX_); qw += (n - zpw) * scw;
        };
        qstep(p0); qstep(p1); qstep(p2); qstep(p3); qstep(p4);
        qstep(p5); qstep(p6); qstep(p7); qstep(p8);

        gx[g][oc] = make_float4(qx, qy, qz, qw);   // reuse exchange buffer
    }
    __syncthreads();

    if (t < 128) {
        float4 f = gx[0][t];
        f = f4add(f, gx[1][t]);
        f = f4add(f, gx[2][t]);
        f = f4add(f, gx[3][t]);
        *(float4*)(out + (size_t)t * L_ + l0) = f;
    }
}

extern "C" void kernel_launch(void* const* d_in, const int* in_sizes, int n_in,
                              void* d_out, int out_size, void* d_ws, size_t ws_size,
                              hipStream_t stream) {
    const float* x    = (const float*)d_in[0];  // 128*32*32
    const float* w    = (const float*)d_in[1];  // 128*1152
    const float* bias = (const float*)d_in[2];  // 128
    float* out = (float*)d_out;                 // 128*1024
    float* ws  = (float*)d_ws;

    const size_t wt_need = (size_t)288 * 128 * 16;   // 576 KB
    if (ws_size >= wt_need) {
        wtrans<<<144, 256, 0, stream>>>(w, ws);
        fused_cas<true><<<256, 512, 0, stream>>>(
            x, w, (const float4*)ws, bias, out);
    } else {
        fused_cas<false><<<256, 512, 0, stream>>>(
            x, w, nullptr, bias, out);
    }
}